// Round 1
// baseline (455.688 us; speedup 1.0000x reference)
//
#include <hip/hip_runtime.h>
#include <hip/hip_bf16.h>

#define B_   4
#define LQ_  900
#define D_   256
#define NH_  8
#define DH_  32
#define NL_  4
#define NP_  4
#define DFF_ 1024
#define LIN_ 21760
#define MQ_  (LQ_*B_)    // 3600
#define MV_  (LIN_*B_)   // 87040

#define BM 128
#define BN 128
#define BK 16
#define LDP (BM+4)       // 132 floats = 528B row stride: 16B-aligned, bank-shifted by 4/k

enum { EPI_NONE=0, EPI_RELU=1, EPI_BF16MASK=2 };

// C[M x N] = A[M x K] @ W[N x K]^T + bias, row-major everything.
template<int N, int K, int EPI>
__global__ __launch_bounds__(256)
void gemm_k(const float* __restrict__ A, const float* __restrict__ W,
            const float* __restrict__ bias, void* __restrict__ Cout,
            int M, const unsigned char* __restrict__ mask)
{
    __shared__ float As[BK][LDP];
    __shared__ float Bs[BK][LDP];
    const int tx = threadIdx.x, ty = threadIdx.y;
    const int tid = ty*16 + tx;
    const int m0 = blockIdx.y * BM;
    const int n0 = blockIdx.x * BN;
    const int lr = tid >> 2;         // 0..63
    const int lc = (tid & 3) * 4;    // 0,4,8,12

    float acc[8][8];
    #pragma unroll
    for (int i = 0; i < 8; ++i)
        #pragma unroll
        for (int j = 0; j < 8; ++j) acc[i][j] = 0.f;

    for (int kt = 0; kt < K; kt += BK) {
        #pragma unroll
        for (int hh = 0; hh < 2; ++hh) {
            int m = m0 + lr + hh*64;
            int ms = m < M ? m : M-1;
            float4 av = *reinterpret_cast<const float4*>(&A[(size_t)ms*K + kt + lc]);
            As[lc+0][lr+hh*64] = av.x;
            As[lc+1][lr+hh*64] = av.y;
            As[lc+2][lr+hh*64] = av.z;
            As[lc+3][lr+hh*64] = av.w;
            int n = n0 + lr + hh*64;   // N is a multiple of BN in all instantiations
            float4 wv = *reinterpret_cast<const float4*>(&W[(size_t)n*K + kt + lc]);
            Bs[lc+0][lr+hh*64] = wv.x;
            Bs[lc+1][lr+hh*64] = wv.y;
            Bs[lc+2][lr+hh*64] = wv.z;
            Bs[lc+3][lr+hh*64] = wv.w;
        }
        __syncthreads();
        #pragma unroll
        for (int k = 0; k < BK; ++k) {
            float a[8], bb[8];
            *reinterpret_cast<float4*>(&a[0])  = *reinterpret_cast<const float4*>(&As[k][ty*8]);
            *reinterpret_cast<float4*>(&a[4])  = *reinterpret_cast<const float4*>(&As[k][ty*8+4]);
            *reinterpret_cast<float4*>(&bb[0]) = *reinterpret_cast<const float4*>(&Bs[k][tx*8]);
            *reinterpret_cast<float4*>(&bb[4]) = *reinterpret_cast<const float4*>(&Bs[k][tx*8+4]);
            #pragma unroll
            for (int i = 0; i < 8; ++i)
                #pragma unroll
                for (int j = 0; j < 8; ++j)
                    acc[i][j] = fmaf(a[i], bb[j], acc[i][j]);
        }
        __syncthreads();
    }

    float bv[8];
    #pragma unroll
    for (int j = 0; j < 8; ++j) bv[j] = bias[n0 + tx*8 + j];

    #pragma unroll
    for (int i = 0; i < 8; ++i) {
        int m = m0 + ty*8 + i;
        if (m >= M) continue;
        if (EPI == EPI_BF16MASK) {
            // value layout row m = i_mem*B_ + b  ->  mask[b*LIN_ + i_mem]
            bool z = mask[(m & 3)*LIN_ + (m >> 2)] != 0;
            union { unsigned short us[8]; uint4 v4; } pk;
            #pragma unroll
            for (int j = 0; j < 8; ++j) {
                float v = acc[i][j] + bv[j];
                if (z) v = 0.f;
                __hip_bfloat16 hv = __float2bfloat16(v);
                pk.us[j] = *reinterpret_cast<unsigned short*>(&hv);
            }
            unsigned short* Cb = reinterpret_cast<unsigned short*>(Cout);
            *reinterpret_cast<uint4*>(&Cb[(size_t)m*N + n0 + tx*8]) = pk.v4;
        } else {
            float v[8];
            #pragma unroll
            for (int j = 0; j < 8; ++j) {
                v[j] = acc[i][j] + bv[j];
                if (EPI == EPI_RELU) v[j] = fmaxf(v[j], 0.f);
            }
            float* Cf = reinterpret_cast<float*>(Cout);
            *reinterpret_cast<float4*>(&Cf[(size_t)m*N + n0 + tx*8])   = *reinterpret_cast<float4*>(&v[0]);
            *reinterpret_cast<float4*>(&Cf[(size_t)m*N + n0 + tx*8+4]) = *reinterpret_cast<float4*>(&v[4]);
        }
    }
}

// one block per (qi,b) row m; thread d = h*32+dh computes msda_out[m][d]
__global__ __launch_bounds__(256)
void msda_k(const float* __restrict__ off,       // [MQ_][256] (h,l,p,2)
            const float* __restrict__ attnlog,   // [MQ_][128] (h,l,p)
            const float* __restrict__ refp,      // (Lq,B,NL,2) flat row m: 8 floats
            const __hip_bfloat16* __restrict__ value, // (Lin,B,256)
            float* __restrict__ out)             // [MQ_][256]
{
    const int m = blockIdx.x;
    const int b = m & 3;
    const int d = threadIdx.x;
    const int h = d >> 5;

    __shared__ float s_off[256];
    __shared__ float s_al[128];
    __shared__ float s_ref[NL_*2];
    s_off[d] = off[(size_t)m*256 + d];
    if (d < 128) s_al[d] = attnlog[(size_t)m*128 + d];
    if (d < NL_*2) s_ref[d] = refp[(size_t)m*(NL_*2) + d];
    __syncthreads();

    // softmax over the 16 (l,p) logits of head h (redundant across 32 dh lanes)
    float mx = -1e30f;
    #pragma unroll
    for (int t = 0; t < 16; ++t) mx = fmaxf(mx, s_al[h*16 + t]);
    float e[16], ssum = 0.f;
    #pragma unroll
    for (int t = 0; t < 16; ++t) { e[t] = __expf(s_al[h*16 + t] - mx); ssum += e[t]; }
    const float inv = 1.f / ssum;

    const int HS[4] = {128, 64, 32, 16};
    const int ST[4] = {0, 16384, 20480, 21504};

    float acc = 0.f;
    #pragma unroll
    for (int l = 0; l < NL_; ++l) {
        const int H = HS[l], W = HS[l], st = ST[l];
        const float rx = s_ref[l*2+0], ry = s_ref[l*2+1];
        #pragma unroll
        for (int p = 0; p < NP_; ++p) {
            const int base = ((h*NL_ + l)*NP_ + p);
            const float a  = e[l*4 + p] * inv;
            const float ox = s_off[base*2+0], oy = s_off[base*2+1];
            // x = (rx + ox/W)*W - 0.5 ; y = (ry + oy/H)*H - 0.5
            const float x = rx*(float)W + ox - 0.5f;   // algebraically identical, fp-close
            const float y = ry*(float)H + oy - 0.5f;
            const float x0f = floorf(x), y0f = floorf(y);
            const int x0 = (int)x0f, y0 = (int)y0f;
            const float wx1 = x - x0f, wy1 = y - y0f;
            const float wx0 = 1.f - wx1, wy0 = 1.f - wy1;
            #pragma unroll
            for (int t = 0; t < 4; ++t) {
                const int xi = x0 + (t & 1);
                const int yi = y0 + (t >> 1);
                const float w = (t==0 ? wx0*wy0 : t==1 ? wx1*wy0 : t==2 ? wx0*wy1 : wx1*wy1);
                if (xi >= 0 && xi < W && yi >= 0 && yi < H) {
                    const size_t idx = (size_t)(st + yi*W + xi);
                    const float v = __bfloat162float(value[(idx*B_ + b)*D_ + d]);
                    acc = fmaf(a*w, v, acc);
                }
            }
        }
    }
    out[(size_t)m*256 + d] = acc;
}

// out[m] = LN(x[m] + r[m]) * g + be   (D_=256, block=256, one row per block)
__global__ __launch_bounds__(256)
void add_ln_k(const float* __restrict__ x, const float* __restrict__ r,
              const float* __restrict__ g, const float* __restrict__ be,
              float* __restrict__ out)
{
    const int m = blockIdx.x, d = threadIdx.x;
    const float v = x[(size_t)m*D_ + d] + r[(size_t)m*D_ + d];
    float s1 = v, s2 = v*v;
    #pragma unroll
    for (int o = 32; o >= 1; o >>= 1) {
        s1 += __shfl_xor(s1, o, 64);
        s2 += __shfl_xor(s2, o, 64);
    }
    __shared__ float r1[4], r2[4];
    const int w = d >> 6;
    if ((d & 63) == 0) { r1[w] = s1; r2[w] = s2; }
    __syncthreads();
    const float t1 = r1[0]+r1[1]+r1[2]+r1[3];
    const float t2 = r2[0]+r2[1]+r2[2]+r2[3];
    const float mu  = t1 * (1.f/D_);
    const float var = t2 * (1.f/D_) - mu*mu;
    const float is  = rsqrtf(var + 1e-5f);
    out[(size_t)m*D_ + d] = (v - mu) * is * g[d] + be[d];
}

extern "C" void kernel_launch(void* const* d_in, const int* in_sizes, int n_in,
                              void* d_out, int out_size, void* d_ws, size_t ws_size,
                              hipStream_t stream)
{
    const float* tgt    = (const float*)d_in[0];
    const float* refp   = (const float*)d_in[1];
    const float* mem    = (const float*)d_in[2];
    const float* W_off  = (const float*)d_in[3];
    const float* b_off  = (const float*)d_in[4];
    const float* W_attn = (const float*)d_in[5];
    const float* b_attn = (const float*)d_in[6];
    const float* W_val  = (const float*)d_in[7];
    const float* b_val  = (const float*)d_in[8];
    const float* W_out  = (const float*)d_in[9];
    const float* b_out  = (const float*)d_in[10];
    const float* ln1g   = (const float*)d_in[11];
    const float* ln1b   = (const float*)d_in[12];
    const float* W1     = (const float*)d_in[13];
    const float* b1     = (const float*)d_in[14];
    const float* W2     = (const float*)d_in[15];
    const float* b2     = (const float*)d_in[16];
    const float* ln3g   = (const float*)d_in[17];
    const float* ln3b   = (const float*)d_in[18];
    const unsigned char* mask = (const unsigned char*)d_in[21];
    float* out = (float*)d_out;

    char* p = (char*)d_ws;
    __hip_bfloat16* value = (__hip_bfloat16*)p; p += (size_t)MV_*D_*2;   // 44.6 MB
    float* offb = (float*)p; p += (size_t)MQ_*256*4;
    float* attl = (float*)p; p += (size_t)MQ_*128*4;
    float* msda = (float*)p; p += (size_t)MQ_*256*4;
    float* ca   = (float*)p; p += (size_t)MQ_*256*4;
    float* tb   = (float*)p; p += (size_t)MQ_*256*4;
    float* hb   = (float*)p; p += (size_t)MQ_*DFF_*4;                    // 14.7 MB
    float* yb   = (float*)p; p += (size_t)MQ_*256*4;
    (void)ws_size; (void)in_sizes; (void)n_in; (void)out_size;

    const dim3 blk(16,16);
    const int gy_q = (MQ_ + BM - 1) / BM;   // 29

    // 1) value = (memory @ W_val^T + b_val), masked, bf16   [87040 x 256]
    gemm_k<256,256,EPI_BF16MASK><<<dim3(2, MV_/BM), blk, 0, stream>>>(mem, W_val, b_val, value, MV_, mask);
    // 2) off = tgt @ W_off^T + b_off    [3600 x 256]
    gemm_k<256,256,EPI_NONE><<<dim3(2, gy_q), blk, 0, stream>>>(tgt, W_off, b_off, offb, MQ_, nullptr);
    // 3) attn logits = tgt @ W_attn^T + b_attn   [3600 x 128]
    gemm_k<128,256,EPI_NONE><<<dim3(1, gy_q), blk, 0, stream>>>(tgt, W_attn, b_attn, attl, MQ_, nullptr);
    // 4) deformable sampling -> msda [3600 x 256]
    msda_k<<<dim3(MQ_), dim3(256), 0, stream>>>(offb, attl, refp, value, msda);
    // 5) ca = msda @ W_out^T + b_out
    gemm_k<256,256,EPI_NONE><<<dim3(2, gy_q), blk, 0, stream>>>(msda, W_out, b_out, ca, MQ_, nullptr);
    // 6) t = LN(tgt + ca)
    add_ln_k<<<dim3(MQ_), dim3(256), 0, stream>>>(ca, tgt, ln1g, ln1b, tb);
    // 7) h = relu(t @ W1^T + b1)   [3600 x 1024]
    gemm_k<DFF_,256,EPI_RELU><<<dim3(DFF_/BN, gy_q), blk, 0, stream>>>(tb, W1, b1, hb, MQ_, nullptr);
    // 8) y = h @ W2^T + b2         [3600 x 256]
    gemm_k<256,DFF_,EPI_NONE><<<dim3(2, gy_q), blk, 0, stream>>>(hb, W2, b2, yb, MQ_, nullptr);
    // 9) out = LN(t + y)
    add_ln_k<<<dim3(MQ_), dim3(256), 0, stream>>>(yb, tb, ln3g, ln3b, out);
}

// Round 2
// 349.692 us; speedup vs baseline: 1.3031x; 1.3031x over previous
//
#include <hip/hip_runtime.h>
#include <hip/hip_bf16.h>

#define B_   4
#define LQ_  900
#define D_   256
#define NH_  8
#define DH_  32
#define NL_  4
#define NP_  4
#define DFF_ 1024
#define LIN_ 21760
#define MQ_  (LQ_*B_)    // 3600
#define MV_  (LIN_*B_)   // 87040

typedef __attribute__((ext_vector_type(8))) short bh8;
typedef __attribute__((ext_vector_type(4))) float f32x4;

__device__ __forceinline__ short bf16b(float f) {
    __hip_bfloat16 h = __float2bfloat16(f);
    return *reinterpret_cast<short*>(&h);
}

// ---------------- value projection: bf16 MFMA GEMM, fused fp32->bf16 ----------------
// C[M x 256] = bf16( mask ? 0 : memory[M x 256] @ W_val[256 x 256]^T + b_val )
#define VBM 128
#define VBN 256
#define VBK 64

__global__ __launch_bounds__(512, 2)
void val_gemm_k(const float* __restrict__ A, const float* __restrict__ W,
                const float* __restrict__ bias, unsigned short* __restrict__ C,
                const unsigned char* __restrict__ mask)
{
    __shared__ __align__(16) short Al[VBM*VBK];   // 16 KB, swizzled
    __shared__ __align__(16) short Wl[VBN*VBK];   // 32 KB, swizzled
    __shared__ unsigned char s_zero[VBM];

    const int tid  = threadIdx.x;
    const int lane = tid & 63;
    const int wid  = tid >> 6;     // 0..7
    const int wr   = wid >> 2;     // 0..1
    const int wc   = wid & 3;      // 0..3
    const int m0   = blockIdx.x * VBM;

    if (tid < VBM) {
        int gm = m0 + tid;
        s_zero[tid] = mask[(gm & 3) * LIN_ + (gm >> 2)];
    }

    f32x4 acc[4][4];
    #pragma unroll
    for (int i = 0; i < 4; ++i)
        #pragma unroll
        for (int j = 0; j < 4; ++j) acc[i][j] = (f32x4){0.f,0.f,0.f,0.f};

    const int lr  = tid >> 4;        // 0..31
    const int lk4 = (tid & 15) * 4;  // col group of 4 within 64

    for (int kt = 0; kt < 256; kt += VBK) {
        __syncthreads();   // protect LDS against previous iteration's readers
        // stage A chunk [128 x 64] fp32 -> bf16 (swizzled)
        #pragma unroll
        for (int sub = 0; sub < 4; ++sub) {
            const int m = lr + sub * 32;
            float4 v = *reinterpret_cast<const float4*>(&A[(size_t)(m0 + m) * 256 + kt + lk4]);
            short4 s = { bf16b(v.x), bf16b(v.y), bf16b(v.z), bf16b(v.w) };
            *reinterpret_cast<short4*>((char*)Al + (((m*128) + lk4*2) ^ ((m & 7) << 4))) = s;
        }
        // stage W chunk [256 x 64] fp32 -> bf16 (swizzled)
        #pragma unroll
        for (int sub = 0; sub < 8; ++sub) {
            const int n = lr + sub * 32;
            float4 v = *reinterpret_cast<const float4*>(&W[(size_t)n * 256 + kt + lk4]);
            short4 s = { bf16b(v.x), bf16b(v.y), bf16b(v.z), bf16b(v.w) };
            *reinterpret_cast<short4*>((char*)Wl + (((n*128) + lk4*2) ^ ((n & 7) << 4))) = s;
        }
        __syncthreads();
        #pragma unroll
        for (int kk = 0; kk < 2; ++kk) {
            const int kb = kk*64 + (lane >> 4) * 16;
            bh8 af[4], bf[4];
            #pragma unroll
            for (int mf = 0; mf < 4; ++mf) {
                const int row = wr*64 + mf*16 + (lane & 15);
                af[mf] = *reinterpret_cast<const bh8*>((char*)Al + ((row*128 + kb) ^ ((row & 7) << 4)));
            }
            #pragma unroll
            for (int nf = 0; nf < 4; ++nf) {
                const int col = wc*64 + nf*16 + (lane & 15);
                bf[nf] = *reinterpret_cast<const bh8*>((char*)Wl + ((col*128 + kb) ^ ((col & 7) << 4)));
            }
            #pragma unroll
            for (int mf = 0; mf < 4; ++mf)
                #pragma unroll
                for (int nf = 0; nf < 4; ++nf)
                    acc[mf][nf] = __builtin_amdgcn_mfma_f32_16x16x32_bf16(af[mf], bf[nf], acc[mf][nf], 0, 0, 0);
        }
    }

    float bv[4];
    #pragma unroll
    for (int nf = 0; nf < 4; ++nf) bv[nf] = bias[wc*64 + nf*16 + (lane & 15)];

    #pragma unroll
    for (int mf = 0; mf < 4; ++mf) {
        #pragma unroll
        for (int r = 0; r < 4; ++r) {
            const int lrow = wr*64 + mf*16 + (lane >> 4)*4 + r;
            const bool z = s_zero[lrow] != 0;
            #pragma unroll
            for (int nf = 0; nf < 4; ++nf) {
                float v = acc[mf][nf][r] + bv[nf];
                if (z) v = 0.f;
                C[(size_t)(m0 + lrow)*256 + wc*64 + nf*16 + (lane & 15)] = (unsigned short)bf16b(v);
            }
        }
    }
}

// ---------------- fp32 tiled GEMM for the small matmuls (unchanged) ----------------
#define BM 128
#define BN 128
#define BK 16
#define LDP (BM+4)

enum { EPI_NONE=0, EPI_RELU=1 };

template<int N, int K, int EPI>
__global__ __launch_bounds__(256)
void gemm_k(const float* __restrict__ A, const float* __restrict__ W,
            const float* __restrict__ bias, float* __restrict__ Cout, int M)
{
    __shared__ float As[BK][LDP];
    __shared__ float Bs[BK][LDP];
    const int tx = threadIdx.x, ty = threadIdx.y;
    const int tid = ty*16 + tx;
    const int m0 = blockIdx.y * BM;
    const int n0 = blockIdx.x * BN;
    const int lr = tid >> 2;
    const int lc = (tid & 3) * 4;

    float acc[8][8];
    #pragma unroll
    for (int i = 0; i < 8; ++i)
        #pragma unroll
        for (int j = 0; j < 8; ++j) acc[i][j] = 0.f;

    for (int kt = 0; kt < K; kt += BK) {
        #pragma unroll
        for (int hh = 0; hh < 2; ++hh) {
            int m = m0 + lr + hh*64;
            int ms = m < M ? m : M-1;
            float4 av = *reinterpret_cast<const float4*>(&A[(size_t)ms*K + kt + lc]);
            As[lc+0][lr+hh*64] = av.x;
            As[lc+1][lr+hh*64] = av.y;
            As[lc+2][lr+hh*64] = av.z;
            As[lc+3][lr+hh*64] = av.w;
            int n = n0 + lr + hh*64;
            float4 wv = *reinterpret_cast<const float4*>(&W[(size_t)n*K + kt + lc]);
            Bs[lc+0][lr+hh*64] = wv.x;
            Bs[lc+1][lr+hh*64] = wv.y;
            Bs[lc+2][lr+hh*64] = wv.z;
            Bs[lc+3][lr+hh*64] = wv.w;
        }
        __syncthreads();
        #pragma unroll
        for (int k = 0; k < BK; ++k) {
            float a[8], bb[8];
            *reinterpret_cast<float4*>(&a[0])  = *reinterpret_cast<const float4*>(&As[k][ty*8]);
            *reinterpret_cast<float4*>(&a[4])  = *reinterpret_cast<const float4*>(&As[k][ty*8+4]);
            *reinterpret_cast<float4*>(&bb[0]) = *reinterpret_cast<const float4*>(&Bs[k][tx*8]);
            *reinterpret_cast<float4*>(&bb[4]) = *reinterpret_cast<const float4*>(&Bs[k][tx*8+4]);
            #pragma unroll
            for (int i = 0; i < 8; ++i)
                #pragma unroll
                for (int j = 0; j < 8; ++j)
                    acc[i][j] = fmaf(a[i], bb[j], acc[i][j]);
        }
        __syncthreads();
    }

    float bvv[8];
    #pragma unroll
    for (int j = 0; j < 8; ++j) bvv[j] = bias[n0 + tx*8 + j];

    #pragma unroll
    for (int i = 0; i < 8; ++i) {
        int m = m0 + ty*8 + i;
        if (m >= M) continue;
        float v[8];
        #pragma unroll
        for (int j = 0; j < 8; ++j) {
            v[j] = acc[i][j] + bvv[j];
            if (EPI == EPI_RELU) v[j] = fmaxf(v[j], 0.f);
        }
        *reinterpret_cast<float4*>(&Cout[(size_t)m*N + n0 + tx*8])   = *reinterpret_cast<float4*>(&v[0]);
        *reinterpret_cast<float4*>(&Cout[(size_t)m*N + n0 + tx*8+4]) = *reinterpret_cast<float4*>(&v[4]);
    }
}

// ---------------- deformable sampling ----------------
__global__ __launch_bounds__(256)
void msda_k(const float* __restrict__ off,
            const float* __restrict__ attnlog,
            const float* __restrict__ refp,
            const __hip_bfloat16* __restrict__ value,
            float* __restrict__ out)
{
    const int m = blockIdx.x;
    const int b = m & 3;
    const int d = threadIdx.x;
    const int h = d >> 5;

    __shared__ float s_off[256];
    __shared__ float s_al[128];
    __shared__ float s_ref[NL_*2];
    s_off[d] = off[(size_t)m*256 + d];
    if (d < 128) s_al[d] = attnlog[(size_t)m*128 + d];
    if (d < NL_*2) s_ref[d] = refp[(size_t)m*(NL_*2) + d];
    __syncthreads();

    float mx = -1e30f;
    #pragma unroll
    for (int t = 0; t < 16; ++t) mx = fmaxf(mx, s_al[h*16 + t]);
    float e[16], ssum = 0.f;
    #pragma unroll
    for (int t = 0; t < 16; ++t) { e[t] = __expf(s_al[h*16 + t] - mx); ssum += e[t]; }
    const float inv = 1.f / ssum;

    const int HS[4] = {128, 64, 32, 16};
    const int ST[4] = {0, 16384, 20480, 21504};

    float acc = 0.f;
    #pragma unroll
    for (int l = 0; l < NL_; ++l) {
        const int H = HS[l], W = HS[l], st = ST[l];
        const float rx = s_ref[l*2+0], ry = s_ref[l*2+1];
        #pragma unroll
        for (int p = 0; p < NP_; ++p) {
            const int base = ((h*NL_ + l)*NP_ + p);
            const float a  = e[l*4 + p] * inv;
            const float ox = s_off[base*2+0], oy = s_off[base*2+1];
            const float x = rx*(float)W + ox - 0.5f;
            const float y = ry*(float)H + oy - 0.5f;
            const float x0f = floorf(x), y0f = floorf(y);
            const int x0 = (int)x0f, y0 = (int)y0f;
            const float wx1 = x - x0f, wy1 = y - y0f;
            const float wx0 = 1.f - wx1, wy0 = 1.f - wy1;
            #pragma unroll
            for (int t = 0; t < 4; ++t) {
                const int xi = x0 + (t & 1);
                const int yi = y0 + (t >> 1);
                const float w = (t==0 ? wx0*wy0 : t==1 ? wx1*wy0 : t==2 ? wx0*wy1 : wx1*wy1);
                if (xi >= 0 && xi < W && yi >= 0 && yi < H) {
                    const size_t idx = (size_t)(st + yi*W + xi);
                    const float v = __bfloat162float(value[(idx*B_ + b)*D_ + d]);
                    acc = fmaf(a*w, v, acc);
                }
            }
        }
    }
    out[(size_t)m*256 + d] = acc;
}

// ---------------- fused add + LayerNorm ----------------
__global__ __launch_bounds__(256)
void add_ln_k(const float* __restrict__ x, const float* __restrict__ r,
              const float* __restrict__ g, const float* __restrict__ be,
              float* __restrict__ out)
{
    const int m = blockIdx.x, d = threadIdx.x;
    const float v = x[(size_t)m*D_ + d] + r[(size_t)m*D_ + d];
    float s1 = v, s2 = v*v;
    #pragma unroll
    for (int o = 32; o >= 1; o >>= 1) {
        s1 += __shfl_xor(s1, o, 64);
        s2 += __shfl_xor(s2, o, 64);
    }
    __shared__ float r1[4], r2[4];
    const int w = d >> 6;
    if ((d & 63) == 0) { r1[w] = s1; r2[w] = s2; }
    __syncthreads();
    const float t1 = r1[0]+r1[1]+r1[2]+r1[3];
    const float t2 = r2[0]+r2[1]+r2[2]+r2[3];
    const float mu  = t1 * (1.f/D_);
    const float var = t2 * (1.f/D_) - mu*mu;
    const float is  = rsqrtf(var + 1e-5f);
    out[(size_t)m*D_ + d] = (v - mu) * is * g[d] + be[d];
}

extern "C" void kernel_launch(void* const* d_in, const int* in_sizes, int n_in,
                              void* d_out, int out_size, void* d_ws, size_t ws_size,
                              hipStream_t stream)
{
    const float* tgt    = (const float*)d_in[0];
    const float* refp   = (const float*)d_in[1];
    const float* mem    = (const float*)d_in[2];
    const float* W_off  = (const float*)d_in[3];
    const float* b_off  = (const float*)d_in[4];
    const float* W_attn = (const float*)d_in[5];
    const float* b_attn = (const float*)d_in[6];
    const float* W_val  = (const float*)d_in[7];
    const float* b_val  = (const float*)d_in[8];
    const float* W_out  = (const float*)d_in[9];
    const float* b_out  = (const float*)d_in[10];
    const float* ln1g   = (const float*)d_in[11];
    const float* ln1b   = (const float*)d_in[12];
    const float* W1     = (const float*)d_in[13];
    const float* b1     = (const float*)d_in[14];
    const float* W2     = (const float*)d_in[15];
    const float* b2     = (const float*)d_in[16];
    const float* ln3g   = (const float*)d_in[17];
    const float* ln3b   = (const float*)d_in[18];
    const unsigned char* mask = (const unsigned char*)d_in[21];
    float* out = (float*)d_out;

    char* p = (char*)d_ws;
    __hip_bfloat16* value = (__hip_bfloat16*)p; p += (size_t)MV_*D_*2;
    float* offb = (float*)p; p += (size_t)MQ_*256*4;
    float* attl = (float*)p; p += (size_t)MQ_*128*4;
    float* msda = (float*)p; p += (size_t)MQ_*256*4;
    float* ca   = (float*)p; p += (size_t)MQ_*256*4;
    float* tb   = (float*)p; p += (size_t)MQ_*256*4;
    float* hb   = (float*)p; p += (size_t)MQ_*DFF_*4;
    float* yb   = (float*)p; p += (size_t)MQ_*256*4;
    (void)ws_size; (void)in_sizes; (void)n_in; (void)out_size;

    const dim3 blk(16,16);
    const int gy_q = (MQ_ + BM - 1) / BM;

    // 1) value = bf16(masked(memory @ W_val^T + b_val))  -- MFMA
    val_gemm_k<<<dim3(MV_/VBM), dim3(512), 0, stream>>>(mem, W_val, b_val,
                                                        (unsigned short*)value, mask);
    // 2) off = tgt @ W_off^T + b_off
    gemm_k<256,256,EPI_NONE><<<dim3(2, gy_q), blk, 0, stream>>>(tgt, W_off, b_off, offb, MQ_);
    // 3) attn logits
    gemm_k<128,256,EPI_NONE><<<dim3(1, gy_q), blk, 0, stream>>>(tgt, W_attn, b_attn, attl, MQ_);
    // 4) deformable sampling
    msda_k<<<dim3(MQ_), dim3(256), 0, stream>>>(offb, attl, refp, value, msda);
    // 5) ca = msda @ W_out^T + b_out
    gemm_k<256,256,EPI_NONE><<<dim3(2, gy_q), blk, 0, stream>>>(msda, W_out, b_out, ca, MQ_);
    // 6) t = LN(tgt + ca)
    add_ln_k<<<dim3(MQ_), dim3(256), 0, stream>>>(ca, tgt, ln1g, ln1b, tb);
    // 7) h = relu(t @ W1^T + b1)
    gemm_k<DFF_,256,EPI_RELU><<<dim3(DFF_/BN, gy_q), blk, 0, stream>>>(tb, W1, b1, hb, MQ_);
    // 8) y = h @ W2^T + b2
    gemm_k<256,DFF_,EPI_NONE><<<dim3(2, gy_q), blk, 0, stream>>>(hb, W2, b2, yb, MQ_);
    // 9) out = LN(t + y)
    add_ln_k<<<dim3(MQ_), dim3(256), 0, stream>>>(yb, tb, ln3g, ln3b, out);
}

// Round 3
// 190.873 us; speedup vs baseline: 2.3874x; 1.8321x over previous
//
#include <hip/hip_runtime.h>
#include <hip/hip_bf16.h>

#define B_   4
#define LQ_  900
#define D_   256
#define NH_  8
#define DH_  32
#define NL_  4
#define NP_  4
#define DFF_ 1024
#define LIN_ 21760
#define MQ_  (LQ_*B_)    // 3600
#define MV_  (LIN_*B_)   // 87040

typedef __attribute__((ext_vector_type(8))) short bh8;
typedef __attribute__((ext_vector_type(4))) float f32x4;

__device__ __forceinline__ short bf16b(float f) {
    __hip_bfloat16 h = __float2bfloat16(f);
    return *reinterpret_cast<short*>(&h);
}

// ---------------- value projection: bf16 MFMA GEMM, fused fp32->bf16 ----------------
#define VBM 128
#define VBN 256
#define VBK 64

__global__ __launch_bounds__(512, 2)
void val_gemm_k(const float* __restrict__ A, const float* __restrict__ W,
                const float* __restrict__ bias, unsigned short* __restrict__ C,
                const unsigned char* __restrict__ mask)
{
    __shared__ __align__(16) short Al[VBM*VBK];   // 16 KB, swizzled
    __shared__ __align__(16) short Wl[VBN*VBK];   // 32 KB, swizzled
    __shared__ unsigned char s_zero[VBM];

    const int tid  = threadIdx.x;
    const int lane = tid & 63;
    const int wid  = tid >> 6;
    const int wr   = wid >> 2;
    const int wc   = wid & 3;
    const int m0   = blockIdx.x * VBM;

    if (tid < VBM) {
        int gm = m0 + tid;
        s_zero[tid] = mask[(gm & 3) * LIN_ + (gm >> 2)];
    }

    f32x4 acc[4][4];
    #pragma unroll
    for (int i = 0; i < 4; ++i)
        #pragma unroll
        for (int j = 0; j < 4; ++j) acc[i][j] = (f32x4){0.f,0.f,0.f,0.f};

    const int lr  = tid >> 4;
    const int lk4 = (tid & 15) * 4;

    for (int kt = 0; kt < 256; kt += VBK) {
        __syncthreads();
        #pragma unroll
        for (int sub = 0; sub < 4; ++sub) {
            const int m = lr + sub * 32;
            float4 v = *reinterpret_cast<const float4*>(&A[(size_t)(m0 + m) * 256 + kt + lk4]);
            short4 s = { bf16b(v.x), bf16b(v.y), bf16b(v.z), bf16b(v.w) };
            *reinterpret_cast<short4*>((char*)Al + (((m*128) + lk4*2) ^ ((m & 7) << 4))) = s;
        }
        #pragma unroll
        for (int sub = 0; sub < 8; ++sub) {
            const int n = lr + sub * 32;
            float4 v = *reinterpret_cast<const float4*>(&W[(size_t)n * 256 + kt + lk4]);
            short4 s = { bf16b(v.x), bf16b(v.y), bf16b(v.z), bf16b(v.w) };
            *reinterpret_cast<short4*>((char*)Wl + (((n*128) + lk4*2) ^ ((n & 7) << 4))) = s;
        }
        __syncthreads();
        #pragma unroll
        for (int kk = 0; kk < 2; ++kk) {
            const int kb = kk*64 + (lane >> 4) * 16;
            bh8 af[4], bf[4];
            #pragma unroll
            for (int mf = 0; mf < 4; ++mf) {
                const int row = wr*64 + mf*16 + (lane & 15);
                af[mf] = *reinterpret_cast<const bh8*>((char*)Al + ((row*128 + kb) ^ ((row & 7) << 4)));
            }
            #pragma unroll
            for (int nf = 0; nf < 4; ++nf) {
                const int col = wc*64 + nf*16 + (lane & 15);
                bf[nf] = *reinterpret_cast<const bh8*>((char*)Wl + ((col*128 + kb) ^ ((col & 7) << 4)));
            }
            #pragma unroll
            for (int mf = 0; mf < 4; ++mf)
                #pragma unroll
                for (int nf = 0; nf < 4; ++nf)
                    acc[mf][nf] = __builtin_amdgcn_mfma_f32_16x16x32_bf16(af[mf], bf[nf], acc[mf][nf], 0, 0, 0);
        }
    }

    float bv[4];
    #pragma unroll
    for (int nf = 0; nf < 4; ++nf) bv[nf] = bias[wc*64 + nf*16 + (lane & 15)];

    #pragma unroll
    for (int mf = 0; mf < 4; ++mf) {
        #pragma unroll
        for (int r = 0; r < 4; ++r) {
            const int lrow = wr*64 + mf*16 + (lane >> 4)*4 + r;
            const bool z = s_zero[lrow] != 0;
            #pragma unroll
            for (int nf = 0; nf < 4; ++nf) {
                float v = acc[mf][nf][r] + bv[nf];
                if (z) v = 0.f;
                C[(size_t)(m0 + lrow)*256 + wc*64 + nf*16 + (lane & 15)] = (unsigned short)bf16b(v);
            }
        }
    }
}

// ---------------- small GEMMs: bf16 MFMA, 64x64 tile, 4 waves ----------------
enum { EPI_NONE=0, EPI_RELU=1 };

template<int N, int K, int EPI>
__global__ __launch_bounds__(256)
void mfma_gemm_k(const float* __restrict__ A, const float* __restrict__ W,
                 const float* __restrict__ bias, float* __restrict__ C, int M)
{
    __shared__ __align__(16) short Al[64*64];   // 8 KB, swizzled (row stride 128 B)
    __shared__ __align__(16) short Wl[64*64];   // 8 KB

    const int tid  = threadIdx.x;
    const int lane = tid & 63;
    const int wid  = tid >> 6;     // 0..3
    const int wr   = wid >> 1;     // 0..1
    const int wc   = wid & 1;      // 0..1
    const int m0   = blockIdx.y * 64;
    const int n0   = blockIdx.x * 64;

    f32x4 acc[2][2];
    #pragma unroll
    for (int i = 0; i < 2; ++i)
        #pragma unroll
        for (int j = 0; j < 2; ++j) acc[i][j] = (f32x4){0.f,0.f,0.f,0.f};

    const int lr  = tid >> 4;        // 0..15
    const int lk4 = (tid & 15) * 4;  // 0..60

    for (int kt = 0; kt < K; kt += 64) {
        __syncthreads();
        #pragma unroll
        for (int sub = 0; sub < 4; ++sub) {
            const int r = lr + sub * 16;
            int gm = m0 + r; if (gm >= M) gm = M - 1;
            float4 v = *reinterpret_cast<const float4*>(&A[(size_t)gm*K + kt + lk4]);
            short4 s = { bf16b(v.x), bf16b(v.y), bf16b(v.z), bf16b(v.w) };
            *reinterpret_cast<short4*>((char*)Al + ((r*128 + lk4*2) ^ ((r & 7) << 4))) = s;
            const int n = n0 + r;     // N always a multiple of 64
            float4 wv = *reinterpret_cast<const float4*>(&W[(size_t)n*K + kt + lk4]);
            short4 sw = { bf16b(wv.x), bf16b(wv.y), bf16b(wv.z), bf16b(wv.w) };
            *reinterpret_cast<short4*>((char*)Wl + ((r*128 + lk4*2) ^ ((r & 7) << 4))) = sw;
        }
        __syncthreads();
        #pragma unroll
        for (int kk = 0; kk < 2; ++kk) {
            const int kb = kk*64 + (lane >> 4) * 16;
            bh8 af[2], bf[2];
            #pragma unroll
            for (int mf = 0; mf < 2; ++mf) {
                const int row = wr*32 + mf*16 + (lane & 15);
                af[mf] = *reinterpret_cast<const bh8*>((char*)Al + ((row*128 + kb) ^ ((row & 7) << 4)));
            }
            #pragma unroll
            for (int nf = 0; nf < 2; ++nf) {
                const int col = wc*32 + nf*16 + (lane & 15);
                bf[nf] = *reinterpret_cast<const bh8*>((char*)Wl + ((col*128 + kb) ^ ((col & 7) << 4)));
            }
            #pragma unroll
            for (int mf = 0; mf < 2; ++mf)
                #pragma unroll
                for (int nf = 0; nf < 2; ++nf)
                    acc[mf][nf] = __builtin_amdgcn_mfma_f32_16x16x32_bf16(af[mf], bf[nf], acc[mf][nf], 0, 0, 0);
        }
    }

    float bv[2];
    #pragma unroll
    for (int nf = 0; nf < 2; ++nf) bv[nf] = bias[n0 + wc*32 + nf*16 + (lane & 15)];

    #pragma unroll
    for (int mf = 0; mf < 2; ++mf) {
        #pragma unroll
        for (int r = 0; r < 4; ++r) {
            const int m = m0 + wr*32 + mf*16 + (lane >> 4)*4 + r;
            if (m >= M) continue;
            #pragma unroll
            for (int nf = 0; nf < 2; ++nf) {
                float v = acc[mf][nf][r] + bv[nf];
                if (EPI == EPI_RELU) v = fmaxf(v, 0.f);
                C[(size_t)m*N + n0 + wc*32 + nf*16 + (lane & 15)] = v;
            }
        }
    }
}

// ---------------- deformable sampling ----------------
__global__ __launch_bounds__(256)
void msda_k(const float* __restrict__ off,
            const float* __restrict__ attnlog,
            const float* __restrict__ refp,
            const __hip_bfloat16* __restrict__ value,
            float* __restrict__ out)
{
    const int m = blockIdx.x;
    const int b = m & 3;
    const int d = threadIdx.x;
    const int h = d >> 5;

    __shared__ float s_off[256];
    __shared__ float s_al[128];
    __shared__ float s_ref[NL_*2];
    s_off[d] = off[(size_t)m*256 + d];
    if (d < 128) s_al[d] = attnlog[(size_t)m*128 + d];
    if (d < NL_*2) s_ref[d] = refp[(size_t)m*(NL_*2) + d];
    __syncthreads();

    float mx = -1e30f;
    #pragma unroll
    for (int t = 0; t < 16; ++t) mx = fmaxf(mx, s_al[h*16 + t]);
    float e[16], ssum = 0.f;
    #pragma unroll
    for (int t = 0; t < 16; ++t) { e[t] = __expf(s_al[h*16 + t] - mx); ssum += e[t]; }
    const float inv = 1.f / ssum;

    const int HS[4] = {128, 64, 32, 16};
    const int ST[4] = {0, 16384, 20480, 21504};

    float acc = 0.f;
    #pragma unroll
    for (int l = 0; l < NL_; ++l) {
        const int H = HS[l], W = HS[l], st = ST[l];
        const float rx = s_ref[l*2+0], ry = s_ref[l*2+1];
        #pragma unroll
        for (int p = 0; p < NP_; ++p) {
            const int base = ((h*NL_ + l)*NP_ + p);
            const float a  = e[l*4 + p] * inv;
            const float ox = s_off[base*2+0], oy = s_off[base*2+1];
            const float x = rx*(float)W + ox - 0.5f;
            const float y = ry*(float)H + oy - 0.5f;
            const float x0f = floorf(x), y0f = floorf(y);
            const int x0 = (int)x0f, y0 = (int)y0f;
            const float wx1 = x - x0f, wy1 = y - y0f;
            const float wx0 = 1.f - wx1, wy0 = 1.f - wy1;
            #pragma unroll
            for (int t = 0; t < 4; ++t) {
                const int xi = x0 + (t & 1);
                const int yi = y0 + (t >> 1);
                const float w = (t==0 ? wx0*wy0 : t==1 ? wx1*wy0 : t==2 ? wx0*wy1 : wx1*wy1);
                if (xi >= 0 && xi < W && yi >= 0 && yi < H) {
                    const size_t idx = (size_t)(st + yi*W + xi);
                    const float v = __bfloat162float(value[(idx*B_ + b)*D_ + d]);
                    acc = fmaf(a*w, v, acc);
                }
            }
        }
    }
    out[(size_t)m*256 + d] = acc;
}

// ---------------- fused add + LayerNorm ----------------
__global__ __launch_bounds__(256)
void add_ln_k(const float* __restrict__ x, const float* __restrict__ r,
              const float* __restrict__ g, const float* __restrict__ be,
              float* __restrict__ out)
{
    const int m = blockIdx.x, d = threadIdx.x;
    const float v = x[(size_t)m*D_ + d] + r[(size_t)m*D_ + d];
    float s1 = v, s2 = v*v;
    #pragma unroll
    for (int o = 32; o >= 1; o >>= 1) {
        s1 += __shfl_xor(s1, o, 64);
        s2 += __shfl_xor(s2, o, 64);
    }
    __shared__ float r1[4], r2[4];
    const int w = d >> 6;
    if ((d & 63) == 0) { r1[w] = s1; r2[w] = s2; }
    __syncthreads();
    const float t1 = r1[0]+r1[1]+r1[2]+r1[3];
    const float t2 = r2[0]+r2[1]+r2[2]+r2[3];
    const float mu  = t1 * (1.f/D_);
    const float var = t2 * (1.f/D_) - mu*mu;
    const float is  = rsqrtf(var + 1e-5f);
    out[(size_t)m*D_ + d] = (v - mu) * is * g[d] + be[d];
}

extern "C" void kernel_launch(void* const* d_in, const int* in_sizes, int n_in,
                              void* d_out, int out_size, void* d_ws, size_t ws_size,
                              hipStream_t stream)
{
    const float* tgt    = (const float*)d_in[0];
    const float* refp   = (const float*)d_in[1];
    const float* mem    = (const float*)d_in[2];
    const float* W_off  = (const float*)d_in[3];
    const float* b_off  = (const float*)d_in[4];
    const float* W_attn = (const float*)d_in[5];
    const float* b_attn = (const float*)d_in[6];
    const float* W_val  = (const float*)d_in[7];
    const float* b_val  = (const float*)d_in[8];
    const float* W_out  = (const float*)d_in[9];
    const float* b_out  = (const float*)d_in[10];
    const float* ln1g   = (const float*)d_in[11];
    const float* ln1b   = (const float*)d_in[12];
    const float* W1     = (const float*)d_in[13];
    const float* b1     = (const float*)d_in[14];
    const float* W2     = (const float*)d_in[15];
    const float* b2     = (const float*)d_in[16];
    const float* ln3g   = (const float*)d_in[17];
    const float* ln3b   = (const float*)d_in[18];
    const unsigned char* mask = (const unsigned char*)d_in[21];
    float* out = (float*)d_out;

    char* p = (char*)d_ws;
    __hip_bfloat16* value = (__hip_bfloat16*)p; p += (size_t)MV_*D_*2;
    float* offb = (float*)p; p += (size_t)MQ_*256*4;
    float* attl = (float*)p; p += (size_t)MQ_*128*4;
    float* msda = (float*)p; p += (size_t)MQ_*256*4;
    float* ca   = (float*)p; p += (size_t)MQ_*256*4;
    float* tb   = (float*)p; p += (size_t)MQ_*256*4;
    float* hb   = (float*)p; p += (size_t)MQ_*DFF_*4;
    float* yb   = (float*)p; p += (size_t)MQ_*256*4;
    (void)ws_size; (void)in_sizes; (void)n_in; (void)out_size;

    const int gy = (MQ_ + 63) / 64;   // 57 m-tiles

    // 1) value = bf16(masked(memory @ W_val^T + b_val))  -- MFMA
    val_gemm_k<<<dim3(MV_/VBM), dim3(512), 0, stream>>>(mem, W_val, b_val,
                                                        (unsigned short*)value, mask);
    // 2) off = tgt @ W_off^T + b_off
    mfma_gemm_k<256,256,EPI_NONE><<<dim3(4, gy), dim3(256), 0, stream>>>(tgt, W_off, b_off, offb, MQ_);
    // 3) attn logits
    mfma_gemm_k<128,256,EPI_NONE><<<dim3(2, gy), dim3(256), 0, stream>>>(tgt, W_attn, b_attn, attl, MQ_);
    // 4) deformable sampling
    msda_k<<<dim3(MQ_), dim3(256), 0, stream>>>(offb, attl, refp, value, msda);
    // 5) ca = msda @ W_out^T + b_out
    mfma_gemm_k<256,256,EPI_NONE><<<dim3(4, gy), dim3(256), 0, stream>>>(msda, W_out, b_out, ca, MQ_);
    // 6) t = LN(tgt + ca)
    add_ln_k<<<dim3(MQ_), dim3(256), 0, stream>>>(ca, tgt, ln1g, ln1b, tb);
    // 7) h = relu(t @ W1^T + b1)
    mfma_gemm_k<DFF_,256,EPI_RELU><<<dim3(16, gy), dim3(256), 0, stream>>>(tb, W1, b1, hb, MQ_);
    // 8) y = h @ W2^T + b2
    mfma_gemm_k<256,DFF_,EPI_NONE><<<dim3(4, gy), dim3(256), 0, stream>>>(hb, W2, b2, yb, MQ_);
    // 9) out = LN(t + y)
    add_ln_k<<<dim3(MQ_), dim3(256), 0, stream>>>(yb, tb, ln3g, ln3b, out);
}